// Round 1
// baseline (203.325 us; speedup 1.0000x reference)
//
#include <hip/hip_runtime.h>
#include <hip/hip_bf16.h>

typedef float f32x4 __attribute__((ext_vector_type(4)));
typedef __bf16 bf16x8 __attribute__((ext_vector_type(8)));

constexpr int B_ = 8, C_ = 256, N_ = 2048, H_ = 4, D_ = 64;
constexpr int BH_ = B_ * H_;  // 32

// ---------------------------------------------------------------------------
// Projection GEMM: y[o,n] = (sum_c w[o,c] * x[c,n] + bias[o]) * scale
// per batch b. Tile 64(o) x 64(n), K=256, 4 waves (2x2), mfma 16x16x32 bf16.
// MODE 0: bf16 out at [((b*H + h)*N + n)*D + d]   (h=o&3, d=o>>2)  -- Q,K
// MODE 1: bf16 out at [((b*H + h)*D + d)*N + n]                    -- V^T
// MODE 2: f32  out at [(b*C + o)*N + n]                            -- final
// ---------------------------------------------------------------------------
template <int IN_BF16, int MODE>
__global__ __launch_bounds__(256) void proj_kernel(
    const void* __restrict__ xin, const float* __restrict__ w,
    const float* __restrict__ bias, void* __restrict__ out, float scale) {
  __shared__ __bf16 a_lds[64][40];   // W tile  [o][k], pad 40
  __shared__ __bf16 bT_lds[64][40];  // X tile transposed [n][k], pad 40

  const int b  = blockIdx.z;
  const int o0 = blockIdx.y * 64;
  const int n0 = blockIdx.x * 64;
  const int t  = threadIdx.x;
  const int lane = t & 63;
  const int wv = t >> 6;
  const int wm = wv >> 1, wn = wv & 1;
  const int l15 = lane & 15, lg = lane >> 4;

  const float*  xf = (const float*)xin;
  const __bf16* xb = (const __bf16*)xin;

  f32x4 acc[2][2] = {};

  for (int k0 = 0; k0 < C_; k0 += 32) {
    // stage W tile [64 o][32 k] -> bf16
    {
      const int row = t >> 2, kk = (t & 3) * 8;
      const float* src = w + (size_t)(o0 + row) * C_ + k0 + kk;
      float4 f0 = *(const float4*)src;
      float4 f1 = *(const float4*)(src + 4);
      bf16x8 p;
      p[0] = (__bf16)f0.x; p[1] = (__bf16)f0.y;
      p[2] = (__bf16)f0.z; p[3] = (__bf16)f0.w;
      p[4] = (__bf16)f1.x; p[5] = (__bf16)f1.y;
      p[6] = (__bf16)f1.z; p[7] = (__bf16)f1.w;
      *(bf16x8*)&a_lds[row][kk] = p;
    }
    // stage X tile [32 k][64 n], transposed into bT[n][k]
    {
      const int kk = t >> 3, ne = (t & 7) * 8;
      __bf16 vals[8];
      if constexpr (IN_BF16) {
        const __bf16* src = xb + ((size_t)b * C_ + k0 + kk) * N_ + n0 + ne;
        bf16x8 v = *(const bf16x8*)src;
        for (int e = 0; e < 8; e++) vals[e] = v[e];
      } else {
        const float* src = xf + ((size_t)b * C_ + k0 + kk) * N_ + n0 + ne;
        float4 f0 = *(const float4*)src;
        float4 f1 = *(const float4*)(src + 4);
        vals[0] = (__bf16)f0.x; vals[1] = (__bf16)f0.y;
        vals[2] = (__bf16)f0.z; vals[3] = (__bf16)f0.w;
        vals[4] = (__bf16)f1.x; vals[5] = (__bf16)f1.y;
        vals[6] = (__bf16)f1.z; vals[7] = (__bf16)f1.w;
      }
      for (int e = 0; e < 8; e++) bT_lds[ne + e][kk] = vals[e];
    }
    __syncthreads();
    bf16x8 af[2], bfr[2];
    af[0]  = *(const bf16x8*)&a_lds[wm * 32 + l15][lg * 8];
    af[1]  = *(const bf16x8*)&a_lds[wm * 32 + 16 + l15][lg * 8];
    bfr[0] = *(const bf16x8*)&bT_lds[wn * 32 + l15][lg * 8];
    bfr[1] = *(const bf16x8*)&bT_lds[wn * 32 + 16 + l15][lg * 8];
    for (int mi = 0; mi < 2; mi++)
      for (int ni = 0; ni < 2; ni++)
        acc[mi][ni] = __builtin_amdgcn_mfma_f32_16x16x32_bf16(
            af[mi], bfr[ni], acc[mi][ni], 0, 0, 0);
    __syncthreads();
  }

  // epilogue: D layout row i = 4*lg + r (=output channel), col j = l15 (=n)
  for (int mi = 0; mi < 2; mi++) {
    for (int r = 0; r < 4; r++) {
      const int och = o0 + wm * 32 + mi * 16 + 4 * lg + r;
      const float bv = bias[och];
      for (int ni = 0; ni < 2; ni++) {
        const int n = n0 + wn * 32 + ni * 16 + l15;
        const float v = (acc[mi][ni][r] + bv) * scale;
        if constexpr (MODE == 0) {
          ((__bf16*)out)[((size_t)(b * H_ + (och & 3)) * N_ + n) * D_ +
                         (och >> 2)] = (__bf16)v;
        } else if constexpr (MODE == 1) {
          ((__bf16*)out)[((size_t)(b * H_ + (och & 3)) * D_ + (och >> 2)) * N_ +
                         n] = (__bf16)v;
        } else {
          ((float*)out)[((size_t)b * C_ + och) * N_ + n] = v;
        }
      }
    }
  }
}

// ---------------------------------------------------------------------------
// Flash attention: per (b,h): O = softmax(Q K^T) V,  Q,K [N,64], V^T [64,N].
// Scale 1/8 pre-folded into Q. Block = 64 q-rows, 4 waves; each wave owns 16
// q-rows x all 64 kv cols (softmax row-reduce is in-wave shfl over lanes 0-15).
// ---------------------------------------------------------------------------
union QOu {
  __bf16 q[64][72];
  float  o[64][68];
};

__global__ __launch_bounds__(256) void attn_kernel(
    const __bf16* __restrict__ qb, const __bf16* __restrict__ kb,
    const __bf16* __restrict__ vtb, __bf16* __restrict__ attout) {
  __shared__ __bf16 k_lds[64][72];
  __shared__ __bf16 vt_lds[64][72];
  __shared__ __bf16 p_lds[64][72];
  __shared__ QOu u;

  const int t = threadIdx.x, lane = t & 63, wv = t >> 6;
  const int l15 = lane & 15, lg = lane >> 4;
  const int bh = blockIdx.y;
  const int qbase = blockIdx.x * 64;
  const __bf16* q_bh  = qb  + (size_t)bh * N_ * D_;
  const __bf16* k_bh  = kb  + (size_t)bh * N_ * D_;
  const __bf16* vt_bh = vtb + (size_t)bh * D_ * N_;

  // stage Q tile [64][64]
  {
    const int row = t >> 2, c16 = (t & 3) * 16;
    const uint4* src = (const uint4*)(q_bh + (size_t)(qbase + row) * D_ + c16);
    *(uint4*)&u.q[row][c16]     = src[0];
    *(uint4*)&u.q[row][c16 + 8] = src[1];
  }
  __syncthreads();
  bf16x8 qf[2];
  qf[0] = *(const bf16x8*)&u.q[wv * 16 + l15][lg * 8];
  qf[1] = *(const bf16x8*)&u.q[wv * 16 + l15][32 + lg * 8];

  f32x4 oacc[4] = {};
  float mrun[4], lrun[4];
  for (int r = 0; r < 4; r++) { mrun[r] = -1e30f; lrun[r] = 0.f; }

  for (int j0 = 0; j0 < N_; j0 += 64) {
    // stage K tile [64 m][64 d] and V^T tile [64 d][64 m]
    {
      const int row = t >> 2, c16 = (t & 3) * 16;
      const uint4* ks = (const uint4*)(k_bh + (size_t)(j0 + row) * D_ + c16);
      *(uint4*)&k_lds[row][c16]     = ks[0];
      *(uint4*)&k_lds[row][c16 + 8] = ks[1];
      const uint4* vs = (const uint4*)(vt_bh + (size_t)row * N_ + j0 + c16);
      *(uint4*)&vt_lds[row][c16]     = vs[0];
      *(uint4*)&vt_lds[row][c16 + 8] = vs[1];
    }
    __syncthreads();

    // S = Q K^T   (16 q-rows x 64 m per wave)
    f32x4 s[4] = {};
    for (int kk = 0; kk < 2; kk++) {
      for (int ni = 0; ni < 4; ni++) {
        bf16x8 kf = *(const bf16x8*)&k_lds[ni * 16 + l15][kk * 32 + lg * 8];
        s[ni] = __builtin_amdgcn_mfma_f32_16x16x32_bf16(qf[kk], kf, s[ni], 0, 0, 0);
      }
    }

    // online softmax (f32); write P to this wave's LDS region as bf16
    for (int r = 0; r < 4; r++) {
      float tm = fmaxf(fmaxf(s[0][r], s[1][r]), fmaxf(s[2][r], s[3][r]));
      tm = fmaxf(tm, __shfl_xor(tm, 1));
      tm = fmaxf(tm, __shfl_xor(tm, 2));
      tm = fmaxf(tm, __shfl_xor(tm, 4));
      tm = fmaxf(tm, __shfl_xor(tm, 8));
      const float mnew = fmaxf(mrun[r], tm);
      const float al = __expf(mrun[r] - mnew);
      mrun[r] = mnew;
      float rs = 0.f;
      for (int ni = 0; ni < 4; ni++) {
        const float p = __expf(s[ni][r] - mnew);
        rs += p;
        p_lds[wv * 16 + 4 * lg + r][ni * 16 + l15] = (__bf16)p;
      }
      rs += __shfl_xor(rs, 1);
      rs += __shfl_xor(rs, 2);
      rs += __shfl_xor(rs, 4);
      rs += __shfl_xor(rs, 8);
      lrun[r] = lrun[r] * al + rs;
      for (int di = 0; di < 4; di++) oacc[di][r] *= al;
    }
    // wave-local LDS handoff (DS ops in-order within a wave); stop compiler reorder
    asm volatile("" ::: "memory");

    // O += P V
    for (int kk = 0; kk < 2; kk++) {
      bf16x8 pf = *(const bf16x8*)&p_lds[wv * 16 + l15][kk * 32 + lg * 8];
      for (int di = 0; di < 4; di++) {
        bf16x8 vf = *(const bf16x8*)&vt_lds[di * 16 + l15][kk * 32 + lg * 8];
        oacc[di] = __builtin_amdgcn_mfma_f32_16x16x32_bf16(pf, vf, oacc[di], 0, 0, 0);
      }
    }
    __syncthreads();
  }

  // normalize, stage O in LDS (f32), then coalesced bf16 store to [B,C,N]
  float inv[4];
  for (int r = 0; r < 4; r++) inv[r] = 1.f / lrun[r];
  for (int di = 0; di < 4; di++)
    for (int r = 0; r < 4; r++)
      u.o[wv * 16 + 4 * lg + r][di * 16 + l15] = oacc[di][r] * inv[r];
  __syncthreads();
  {
    const int d = t >> 2, q16 = (t & 3) * 16;
    bf16x8 pk[2];
    for (int e = 0; e < 16; e++) {
      pk[e >> 3][e & 7] = (__bf16)u.o[q16 + e][d];
    }
    const int b = bh >> 2, h = bh & 3;
    __bf16* dst = attout + ((size_t)b * C_ + d * H_ + h) * N_ + qbase + q16;
    *(bf16x8*)dst = pk[0];
    *(bf16x8*)(dst + 8) = pk[1];
  }
}

extern "C" void kernel_launch(void* const* d_in, const int* in_sizes, int n_in,
                              void* d_out, int out_size, void* d_ws,
                              size_t ws_size, hipStream_t stream) {
  const float* query = (const float*)d_in[0];
  const float* key_  = (const float*)d_in[1];
  const float* value = (const float*)d_in[2];
  const float* wq = (const float*)d_in[3];
  const float* bq = (const float*)d_in[4];
  const float* wk = (const float*)d_in[5];
  const float* bk = (const float*)d_in[6];
  const float* wv = (const float*)d_in[7];
  const float* bv = (const float*)d_in[8];
  const float* wm = (const float*)d_in[9];
  const float* bm = (const float*)d_in[10];

  const size_t per = (size_t)BH_ * N_ * D_;  // 4M elems = 8MB bf16
  __bf16* qb     = (__bf16*)d_ws;
  __bf16* kb     = qb + per;
  __bf16* vtb    = kb + per;
  __bf16* attout = vtb + per;

  dim3 pgrid(N_ / 64, C_ / 64, B_);
  dim3 blk(256);
  // scale 1/sqrt(64) = 0.125 folded into Q (exact power of two in bf16)
  proj_kernel<0, 0><<<pgrid, blk, 0, stream>>>(query, wq, bq, qb, 0.125f);
  proj_kernel<0, 0><<<pgrid, blk, 0, stream>>>(key_, wk, bk, kb, 1.0f);
  proj_kernel<0, 1><<<pgrid, blk, 0, stream>>>(value, wv, bv, vtb, 1.0f);
  attn_kernel<<<dim3(N_ / 64, BH_), blk, 0, stream>>>(qb, kb, vtb, attout);
  proj_kernel<1, 2><<<pgrid, blk, 0, stream>>>(attout, wm, bm, d_out, 1.0f);
}

// Round 2
// 144.531 us; speedup vs baseline: 1.4068x; 1.4068x over previous
//
#include <hip/hip_runtime.h>
#include <hip/hip_bf16.h>

typedef float f32x4 __attribute__((ext_vector_type(4)));
typedef __bf16 bf16x8 __attribute__((ext_vector_type(8)));
typedef __bf16 bf16x4 __attribute__((ext_vector_type(4)));

constexpr int B_ = 8, C_ = 256, N_ = 2048, H_ = 4, D_ = 64;
constexpr int BH_ = B_ * H_;  // 32
constexpr float LOG2E = 1.44269504088896340736f;

// ---------------------------------------------------------------------------
// W pre-convert: f32 [256][256] -> bf16 in A-fragment order:
//   wf[((o_blk*8 + ks)*64 + lane)*8 + e] = w[o_blk*16 + (lane&15)][ks*32 + (lane>>4)*8 + e]
// so proj reads its MFMA A-fragment as one contiguous 16B load (L2-resident).
// ---------------------------------------------------------------------------
struct W4 {
  const float* s0; const float* s1; const float* s2; const float* s3;
  __bf16* d0; __bf16* d1; __bf16* d2; __bf16* d3;
};

__global__ __launch_bounds__(256) void wcvt_kernel(W4 p) {
  const int m = blockIdx.y;
  const float* src = m == 0 ? p.s0 : m == 1 ? p.s1 : m == 2 ? p.s2 : p.s3;
  __bf16* dst = m == 0 ? p.d0 : m == 1 ? p.d1 : m == 2 ? p.d2 : p.d3;
  const int f = blockIdx.x * 256 + threadIdx.x;  // 0..8191 fragment ids
  const int o_blk = f >> 9;
  const int ks = (f >> 6) & 7;
  const int lane = f & 63;
  const int row = o_blk * 16 + (lane & 15);
  const int col = ks * 32 + (lane >> 4) * 8;
  const float* s = src + row * 256 + col;
  float4 a = *(const float4*)s;
  float4 b = *(const float4*)(s + 4);
  bf16x8 v;
  v[0] = (__bf16)a.x; v[1] = (__bf16)a.y; v[2] = (__bf16)a.z; v[3] = (__bf16)a.w;
  v[4] = (__bf16)b.x; v[5] = (__bf16)b.y; v[6] = (__bf16)b.z; v[7] = (__bf16)b.w;
  *(bf16x8*)&dst[(size_t)f * 8] = v;
}

// ---------------------------------------------------------------------------
// Projection GEMM, LDS-free: y[o,n] = (sum_c w[o,c]*x[c,n] + bias[o]) * scale.
// W from fragment-ordered bf16 (L2), X B-fragments loaded direct from global
// (coalesced dwords, cvt in flight). Tile 64(o) x 64(n), 4 waves (2x2).
// XCD-bijective work-id swizzle co-schedules the 4 o-tiles of one (b,n) chunk.
// MODE 0: bf16 out at [((b*H + h)*N + n)*D + d]   (h=o&3, d=o>>2)  -- Q,K
// MODE 1: bf16 out at [((b*H + h)*D + d)*N + n]                    -- V^T
// MODE 2: f32  out at [(b*C + o)*N + n]                            -- final
// ---------------------------------------------------------------------------
template <int IN_BF16, int MODE>
__global__ __launch_bounds__(256) void proj_kernel(
    const void* __restrict__ xin, const __bf16* __restrict__ wf,
    const float* __restrict__ bias, void* __restrict__ out, float scale) {
  const int bid = blockIdx.x;                 // 1024 blocks
  const int wid = (bid & 7) * 128 + (bid >> 3);  // bijective XCD swizzle
  const int o_t = wid & 3;
  const int nb = (wid >> 2) & 31;
  const int b = wid >> 7;
  const int o0 = o_t * 64, n0 = nb * 64;
  const int t = threadIdx.x, lane = t & 63;
  const int wv = t >> 6, wm = wv >> 1, wn = wv & 1;
  const int l15 = lane & 15, lg = lane >> 4;

  const float* xf = (const float*)xin;
  const __bf16* xb = (const __bf16*)xin;
  const int nbase = n0 + wn * 32 + l15;

  f32x4 acc[2][2] = {};

  for (int ks = 0; ks < 8; ks++) {
    bf16x8 af[2];
    for (int mi = 0; mi < 2; mi++)
      af[mi] = *(const bf16x8*)&wf[(((size_t)(o_t * 4 + wm * 2 + mi) * 8 + ks) * 64 + lane) * 8];
    bf16x8 bfr[2];
    const int krow = ks * 32 + lg * 8;
    for (int ni = 0; ni < 2; ni++) {
      const int n = nbase + ni * 16;
      if constexpr (IN_BF16) {
        for (int e = 0; e < 8; e++)
          bfr[ni][e] = xb[((size_t)b * C_ + krow + e) * N_ + n];
      } else {
        for (int e = 0; e < 8; e++)
          bfr[ni][e] = (__bf16)xf[((size_t)b * C_ + krow + e) * N_ + n];
      }
    }
    for (int mi = 0; mi < 2; mi++)
      for (int ni = 0; ni < 2; ni++)
        acc[mi][ni] = __builtin_amdgcn_mfma_f32_16x16x32_bf16(
            af[mi], bfr[ni], acc[mi][ni], 0, 0, 0);
  }

  for (int mi = 0; mi < 2; mi++) {
    for (int r = 0; r < 4; r++) {
      const int och = o0 + wm * 32 + mi * 16 + 4 * lg + r;
      const float bv = bias[och];
      for (int ni = 0; ni < 2; ni++) {
        const int n = n0 + wn * 32 + ni * 16 + l15;
        const float v = (acc[mi][ni][r] + bv) * scale;
        if constexpr (MODE == 0) {
          ((__bf16*)out)[((size_t)(b * H_ + (och & 3)) * N_ + n) * D_ + (och >> 2)] = (__bf16)v;
        } else if constexpr (MODE == 1) {
          ((__bf16*)out)[((size_t)(b * H_ + (och & 3)) * D_ + (och >> 2)) * N_ + n] = (__bf16)v;
        } else {
          ((float*)out)[((size_t)b * C_ + och) * N_ + n] = v;
        }
      }
    }
  }
}

// ---------------------------------------------------------------------------
// Flash attention, swapped-operand form. Per (b,h): O = softmax(Q K^T) V.
// Q pre-scaled by log2(e)/8 so softmax runs in exp2.
// S = mfma(K, Q): lane holds S[k=ni*16+4*lg+r][q=l15] -> one q-row per lane,
// scalar (m,l) state, row-reduce = 2 shfl_xor. P packed to LDS as b64.
// O = mfma(V^T, P): lane holds O[d][q=l15] -> direct coalesced-ish global store.
// ---------------------------------------------------------------------------
__global__ __launch_bounds__(256) void attn_kernel(
    const __bf16* __restrict__ qb, const __bf16* __restrict__ kb,
    const __bf16* __restrict__ vtb, __bf16* __restrict__ attout) {
  __shared__ __bf16 k_lds[64][72];
  __shared__ __bf16 vt_lds[64][72];
  __shared__ __bf16 p_lds[64][72];  // rows wv*16+l15 (one wave's 16 q-rows)

  const int t = threadIdx.x, lane = t & 63, wv = t >> 6;
  const int l15 = lane & 15, lg = lane >> 4;
  const int bh = blockIdx.y;
  const int qbase = blockIdx.x * 64;
  const __bf16* k_bh = kb + (size_t)bh * N_ * D_;
  const __bf16* vt_bh = vtb + (size_t)bh * D_ * N_;

  // Q fragments straight from global (each row fully covered by its wave)
  const __bf16* qrow = qb + ((size_t)bh * N_ + qbase + wv * 16 + l15) * D_;
  bf16x8 qf0 = *(const bf16x8*)(qrow + lg * 8);
  bf16x8 qf1 = *(const bf16x8*)(qrow + 32 + lg * 8);

  f32x4 oacc[4] = {};
  float mrun = -3e38f, lrun = 0.f;

  for (int j0 = 0; j0 < N_; j0 += 64) {
    {
      const int row = t >> 2, c16 = (t & 3) * 16;
      const uint4* ksrc = (const uint4*)(k_bh + (size_t)(j0 + row) * D_ + c16);
      *(uint4*)&k_lds[row][c16] = ksrc[0];
      *(uint4*)&k_lds[row][c16 + 8] = ksrc[1];
      const uint4* vsrc = (const uint4*)(vt_bh + (size_t)row * N_ + j0 + c16);
      *(uint4*)&vt_lds[row][c16] = vsrc[0];
      *(uint4*)&vt_lds[row][c16 + 8] = vsrc[1];
    }
    __syncthreads();

    // S^T tile: s[ni][r] = S[k = j0 + ni*16 + 4*lg + r][q = l15]
    f32x4 s[4] = {};
    __builtin_amdgcn_s_setprio(1);
    for (int ni = 0; ni < 4; ni++) {
      bf16x8 kf0 = *(const bf16x8*)&k_lds[ni * 16 + l15][lg * 8];
      bf16x8 kf1 = *(const bf16x8*)&k_lds[ni * 16 + l15][32 + lg * 8];
      s[ni] = __builtin_amdgcn_mfma_f32_16x16x32_bf16(kf0, qf0, s[ni], 0, 0, 0);
      s[ni] = __builtin_amdgcn_mfma_f32_16x16x32_bf16(kf1, qf1, s[ni], 0, 0, 0);
    }
    __builtin_amdgcn_s_setprio(0);

    // online softmax, scalar per lane (q = l15); log2-domain
    float tm = s[0][0];
    for (int ni = 0; ni < 4; ni++)
      for (int r = 0; r < 4; r++) tm = fmaxf(tm, s[ni][r]);
    tm = fmaxf(tm, __shfl_xor(tm, 16));
    tm = fmaxf(tm, __shfl_xor(tm, 32));
    if (__any(tm > mrun)) {  // exact: skip rescale only when no row grew
      const float mnew = fmaxf(mrun, tm);
      const float al = exp2f(mrun - mnew);
      mrun = mnew;
      lrun *= al;
      for (int di = 0; di < 4; di++) oacc[di] *= al;
    }
    float rs = 0.f;
    for (int ni = 0; ni < 4; ni++) {
      bf16x4 pk;
      for (int r = 0; r < 4; r++) {
        const float p = exp2f(s[ni][r] - mrun);
        rs += p;
        pk[r] = (__bf16)p;
      }
      *(bf16x4*)&p_lds[wv * 16 + l15][ni * 16 + 4 * lg] = pk;
    }
    rs += __shfl_xor(rs, 16);
    rs += __shfl_xor(rs, 32);
    lrun += rs;
    asm volatile("" ::: "memory");  // keep P writes before PV reads (wave-local)

    // O^T += V^T P : oacc[di][r] = O[d = di*16+4*lg+r][q = l15]
    __builtin_amdgcn_s_setprio(1);
    for (int kk = 0; kk < 2; kk++) {
      bf16x8 pf = *(const bf16x8*)&p_lds[wv * 16 + l15][kk * 32 + lg * 8];
      for (int di = 0; di < 4; di++) {
        bf16x8 vf = *(const bf16x8*)&vt_lds[di * 16 + l15][kk * 32 + lg * 8];
        oacc[di] = __builtin_amdgcn_mfma_f32_16x16x32_bf16(vf, pf, oacc[di], 0, 0, 0);
      }
    }
    __builtin_amdgcn_s_setprio(0);
    __syncthreads();
  }

  // direct store: c = d*H + h, n = qbase + wv*16 + l15
  const float inv = 1.f / lrun;
  const int b = bh >> 2, h = bh & 3;
  const int n = qbase + wv * 16 + l15;
  for (int di = 0; di < 4; di++) {
    for (int r = 0; r < 4; r++) {
      const int d = di * 16 + 4 * lg + r;
      attout[((size_t)(b * C_ + d * H_ + h)) * N_ + n] = (__bf16)(oacc[di][r] * inv);
    }
  }
}

extern "C" void kernel_launch(void* const* d_in, const int* in_sizes, int n_in,
                              void* d_out, int out_size, void* d_ws,
                              size_t ws_size, hipStream_t stream) {
  const float* query = (const float*)d_in[0];
  const float* key_ = (const float*)d_in[1];
  const float* value = (const float*)d_in[2];
  const float* wq = (const float*)d_in[3];
  const float* bq = (const float*)d_in[4];
  const float* wk = (const float*)d_in[5];
  const float* bk = (const float*)d_in[6];
  const float* wv = (const float*)d_in[7];
  const float* bv = (const float*)d_in[8];
  const float* wm = (const float*)d_in[9];
  const float* bm = (const float*)d_in[10];

  const size_t per = (size_t)BH_ * N_ * D_;  // 4M elems = 8MB bf16
  __bf16* qb = (__bf16*)d_ws;
  __bf16* kb = qb + per;
  __bf16* vtb = kb + per;
  __bf16* attout = vtb + per;
  __bf16* wfq = attout + per;          // 64K elems each
  __bf16* wfk = wfq + 65536;
  __bf16* wfv = wfk + 65536;
  __bf16* wfm = wfv + 65536;

  dim3 blk(256);
  W4 wp{wq, wk, wv, wm, wfq, wfk, wfv, wfm};
  wcvt_kernel<<<dim3(32, 4), blk, 0, stream>>>(wp);

  // scale log2(e)/8 folded into Q so attention softmax runs in exp2 domain
  proj_kernel<0, 0><<<1024, blk, 0, stream>>>(query, wfq, bq, qb, 0.125f * LOG2E);
  proj_kernel<0, 0><<<1024, blk, 0, stream>>>(key_, wfk, bk, kb, 1.0f);
  proj_kernel<0, 1><<<1024, blk, 0, stream>>>(value, wfv, bv, vtb, 1.0f);
  attn_kernel<<<dim3(N_ / 64, BH_), blk, 0, stream>>>(qb, kb, vtb, attout);
  proj_kernel<1, 2><<<1024, blk, 0, stream>>>(attout, wfm, bm, d_out, 1.0f);
}

// Round 3
// 124.612 us; speedup vs baseline: 1.6317x; 1.1598x over previous
//
#include <hip/hip_runtime.h>
#include <hip/hip_bf16.h>

typedef float f32x4 __attribute__((ext_vector_type(4)));
typedef __bf16 bf16x8 __attribute__((ext_vector_type(8)));
typedef __bf16 bf16x4 __attribute__((ext_vector_type(4)));

constexpr int B_ = 8, C_ = 256, N_ = 2048, H_ = 4, D_ = 64;
constexpr int BH_ = B_ * H_;  // 32
constexpr float LOG2E = 1.44269504088896340736f;

static __device__ __forceinline__ float fast_exp2(float x) {
#if __has_builtin(__builtin_amdgcn_exp2f)
  return __builtin_amdgcn_exp2f(x);
#else
  return exp2f(x);
#endif
}

// XOR swizzle for [rows][128B] LDS tiles: spread 16B slots across banks.
// Applied on BOTH write and read (reg-staged, rule #21).
static __device__ __forceinline__ void* swz(void* base, int row, int cb) {
  return (char*)base + row * 128 + (cb ^ ((row & 7) << 4));
}
static __device__ __forceinline__ const void* swz(const void* base, int row, int cb) {
  return (const char*)base + row * 128 + (cb ^ ((row & 7) << 4));
}

// ---------------------------------------------------------------------------
// W pre-convert: f32 [256][256] -> bf16 in A-fragment order:
//   wf[((o_blk*8 + ks)*64 + lane)*8 + e] = w[o_blk*16 + (lane&15)][ks*32 + (lane>>4)*8 + e]
// m==3 (wm): columns permuted so the final proj can read attout in
// [B][N][h*64+d] order: W'[o][k] = wm[o][ ((k&63)<<2) | (k>>6) ].
// ---------------------------------------------------------------------------
struct W4 {
  const float* s0; const float* s1; const float* s2; const float* s3;
  __bf16* d0; __bf16* d1; __bf16* d2; __bf16* d3;
};

__global__ __launch_bounds__(256) void wcvt_kernel(W4 p) {
  const int m = blockIdx.y;
  const float* src = m == 0 ? p.s0 : m == 1 ? p.s1 : m == 2 ? p.s2 : p.s3;
  __bf16* dst = m == 0 ? p.d0 : m == 1 ? p.d1 : m == 2 ? p.d2 : p.d3;
  const int f = blockIdx.x * 256 + threadIdx.x;  // 0..8191 fragment ids
  const int o_blk = f >> 9;
  const int ks = (f >> 6) & 7;
  const int lane = f & 63;
  const int row = o_blk * 16 + (lane & 15);
  const int kbase = ks * 32 + (lane >> 4) * 8;
  bf16x8 v;
  if (m == 3) {
    for (int e = 0; e < 8; e++) {
      const int k = kbase + e;
      const int c = ((k & 63) << 2) | (k >> 6);
      v[e] = (__bf16)src[row * 256 + c];
    }
  } else {
    const float* s = src + row * 256 + kbase;
    float4 a = *(const float4*)s;
    float4 b = *(const float4*)(s + 4);
    v[0] = (__bf16)a.x; v[1] = (__bf16)a.y; v[2] = (__bf16)a.z; v[3] = (__bf16)a.w;
    v[4] = (__bf16)b.x; v[5] = (__bf16)b.y; v[6] = (__bf16)b.z; v[7] = (__bf16)b.w;
  }
  *(bf16x8*)&dst[(size_t)f * 8] = v;
}

// ---------------------------------------------------------------------------
// Merged Q/K/V projection, LDS-free. blockIdx.x: [0,3072) = m*1024 + inner.
// y[o,n] = (sum_c w[o,c]*x[c,n] + bias[o]) * scale, per batch b.
// m=0,1 (Q,K): bf16 out at [((b*H + h)*N + n)*D + d]  (h=o&3, d=o>>2)
// m=2   (V):   bf16 out at [((b*H + h)*D + d)*N + n]  (V^T)
// ---------------------------------------------------------------------------
__global__ __launch_bounds__(256) void qkv_proj_kernel(
    const float* __restrict__ xq, const float* __restrict__ xk,
    const float* __restrict__ xv, const __bf16* __restrict__ wfq,
    const __bf16* __restrict__ wfk, const __bf16* __restrict__ wfv,
    const float* __restrict__ bq, const float* __restrict__ bk,
    const float* __restrict__ bv, __bf16* __restrict__ oq,
    __bf16* __restrict__ ok, __bf16* __restrict__ ov) {
  const int m = blockIdx.x >> 10;
  const int bid = blockIdx.x & 1023;
  const float* xf = m == 0 ? xq : m == 1 ? xk : xv;
  const __bf16* wf = m == 0 ? wfq : m == 1 ? wfk : wfv;
  const float* bias = m == 0 ? bq : m == 1 ? bk : bv;
  __bf16* out = m == 0 ? oq : m == 1 ? ok : ov;
  const float scale = m == 0 ? 0.125f * LOG2E : 1.0f;

  const int wid = (bid & 7) * 128 + (bid >> 3);  // bijective XCD swizzle
  const int o_t = wid & 3;
  const int nb = (wid >> 2) & 31;
  const int b = wid >> 7;
  const int o0 = o_t * 64, n0 = nb * 64;
  const int t = threadIdx.x, lane = t & 63;
  const int wv = t >> 6, wm = wv >> 1, wn = wv & 1;
  const int l15 = lane & 15, lg = lane >> 4;
  const int nbase = n0 + wn * 32 + l15;

  f32x4 acc[2][2] = {};

  for (int ks = 0; ks < 8; ks++) {
    bf16x8 af[2];
    for (int mi = 0; mi < 2; mi++)
      af[mi] = *(const bf16x8*)&wf[(((size_t)(o_t * 4 + wm * 2 + mi) * 8 + ks) * 64 + lane) * 8];
    bf16x8 bfr[2];
    const int krow = ks * 32 + lg * 8;
    for (int ni = 0; ni < 2; ni++) {
      const int n = nbase + ni * 16;
      for (int e = 0; e < 8; e++)
        bfr[ni][e] = (__bf16)xf[((size_t)b * C_ + krow + e) * N_ + n];
    }
    for (int mi = 0; mi < 2; mi++)
      for (int ni = 0; ni < 2; ni++)
        acc[mi][ni] = __builtin_amdgcn_mfma_f32_16x16x32_bf16(
            af[mi], bfr[ni], acc[mi][ni], 0, 0, 0);
  }

  for (int mi = 0; mi < 2; mi++) {
    for (int r = 0; r < 4; r++) {
      const int och = o0 + wm * 32 + mi * 16 + 4 * lg + r;
      const float bv_ = bias[och];
      for (int ni = 0; ni < 2; ni++) {
        const int n = n0 + wn * 32 + ni * 16 + l15;
        const float v = (acc[mi][ni][r] + bv_) * scale;
        if (m != 2) {
          out[((size_t)(b * H_ + (och & 3)) * N_ + n) * D_ + (och >> 2)] = (__bf16)v;
        } else {
          out[((size_t)(b * H_ + (och & 3)) * D_ + (och >> 2)) * N_ + n] = (__bf16)v;
        }
      }
    }
  }
}

// ---------------------------------------------------------------------------
// Final projection: y[o,n] = sum_k w'[o,k]*attout[b,n,k] + bm[o], f32 out.
// attout is [B][N][256] with k = h*64+d (wm columns pre-permuted in wcvt).
// B-fragments are single contiguous 16B bf16x8 loads.
// ---------------------------------------------------------------------------
__global__ __launch_bounds__(256) void final_proj_kernel(
    const __bf16* __restrict__ xb, const __bf16* __restrict__ wf,
    const float* __restrict__ bias, float* __restrict__ out) {
  const int bid = blockIdx.x;
  const int wid = (bid & 7) * 128 + (bid >> 3);
  const int o_t = wid & 3;
  const int nb = (wid >> 2) & 31;
  const int b = wid >> 7;
  const int o0 = o_t * 64, n0 = nb * 64;
  const int t = threadIdx.x, lane = t & 63;
  const int wv = t >> 6, wm = wv >> 1, wn = wv & 1;
  const int l15 = lane & 15, lg = lane >> 4;
  const int nbase = n0 + wn * 32 + l15;

  f32x4 acc[2][2] = {};

  for (int ks = 0; ks < 8; ks++) {
    bf16x8 af[2];
    for (int mi = 0; mi < 2; mi++)
      af[mi] = *(const bf16x8*)&wf[(((size_t)(o_t * 4 + wm * 2 + mi) * 8 + ks) * 64 + lane) * 8];
    bf16x8 bfr[2];
    for (int ni = 0; ni < 2; ni++) {
      const int n = nbase + ni * 16;
      bfr[ni] = *(const bf16x8*)&xb[((size_t)b * N_ + n) * C_ + ks * 32 + lg * 8];
    }
    for (int mi = 0; mi < 2; mi++)
      for (int ni = 0; ni < 2; ni++)
        acc[mi][ni] = __builtin_amdgcn_mfma_f32_16x16x32_bf16(
            af[mi], bfr[ni], acc[mi][ni], 0, 0, 0);
  }

  for (int mi = 0; mi < 2; mi++) {
    for (int r = 0; r < 4; r++) {
      const int och = o0 + wm * 32 + mi * 16 + 4 * lg + r;
      const float bv_ = bias[och];
      for (int ni = 0; ni < 2; ni++) {
        const int n = n0 + wn * 32 + ni * 16 + l15;
        out[((size_t)b * C_ + och) * N_ + n] = acc[mi][ni][r] + bv_;
      }
    }
  }
}

// ---------------------------------------------------------------------------
// Flash attention, swapped-operand, double-buffered, 1 barrier/tile.
// Per (b,h): O = softmax(Q K^T) V. Q pre-scaled by log2(e)/8 (exp2 domain).
// S = mfma(K,Q): lane holds S[k=ni*16+4*lg+r][q=l15]; scalar (m,l) state.
// Defer-max: rescale only when max grows by >8 (log2 units); P <= 2^8.
// O = mfma(V^T,P); epilogue transposes O per-wave in LDS and stores
// attout[b][n][h*64+d] coalesced.
// ---------------------------------------------------------------------------
__global__ __launch_bounds__(256) void attn_kernel(
    const __bf16* __restrict__ qb, const __bf16* __restrict__ kb,
    const __bf16* __restrict__ vtb, __bf16* __restrict__ attout) {
  __shared__ __bf16 kbuf[2][64][64];
  __shared__ __bf16 vtbuf[2][64][64];
  __shared__ __bf16 p_lds[64][64];  // per-wave-private rows wv*16..wv*16+15

  const int t = threadIdx.x, lane = t & 63, wv = t >> 6;
  const int l15 = lane & 15, lg = lane >> 4;

  const int bid = blockIdx.x;
  const int wid = (bid & 7) * 128 + (bid >> 3);  // 4 bh per XCD -> K/V L2-resident
  const int bh = wid >> 5;
  const int qbase = (wid & 31) * 64;

  const __bf16* k_bh = kb + (size_t)bh * N_ * D_;
  const __bf16* vt_bh = vtb + (size_t)bh * D_ * N_;

  // Q fragments straight from global
  const __bf16* qrow = qb + ((size_t)bh * N_ + qbase + wv * 16 + l15) * D_;
  const bf16x8 qf0 = *(const bf16x8*)(qrow + lg * 8);
  const bf16x8 qf1 = *(const bf16x8*)(qrow + 32 + lg * 8);

  const int srow = t >> 2, sce = (t & 3) * 16;  // staging: row, elem-col

  // prologue: stage tile 0 into buffer 0
  {
    uint4 ka = *(const uint4*)(k_bh + (size_t)srow * D_ + sce);
    uint4 kc = *(const uint4*)(k_bh + (size_t)srow * D_ + sce + 8);
    uint4 va = *(const uint4*)(vt_bh + (size_t)srow * N_ + sce);
    uint4 vc = *(const uint4*)(vt_bh + (size_t)srow * N_ + sce + 8);
    *(uint4*)swz(&kbuf[0][0][0], srow, sce * 2) = ka;
    *(uint4*)swz(&kbuf[0][0][0], srow, sce * 2 + 16) = kc;
    *(uint4*)swz(&vtbuf[0][0][0], srow, sce * 2) = va;
    *(uint4*)swz(&vtbuf[0][0][0], srow, sce * 2 + 16) = vc;
  }
  __syncthreads();

  f32x4 oacc[4] = {};
  float mrun = -3e38f, lrun = 0.f;
  int cur = 0;

  for (int j0 = 0; j0 < N_; j0 += 64) {
    const int jn = j0 + 64;
    const bool have = jn < N_;
    uint4 pka, pkc, pva, pvc;
    if (have) {  // T14: issue next-tile loads early; write after compute
      pka = *(const uint4*)(k_bh + (size_t)(jn + srow) * D_ + sce);
      pkc = *(const uint4*)(k_bh + (size_t)(jn + srow) * D_ + sce + 8);
      pva = *(const uint4*)(vt_bh + (size_t)srow * N_ + jn + sce);
      pvc = *(const uint4*)(vt_bh + (size_t)srow * N_ + jn + sce + 8);
    }

    // S^T: s[ni][r] = S[k = j0 + ni*16 + 4*lg + r][q = l15]
    f32x4 s[4] = {};
    __builtin_amdgcn_s_setprio(1);
    for (int ni = 0; ni < 4; ni++) {
      bf16x8 kf0 = *(const bf16x8*)swz(&kbuf[cur][0][0], ni * 16 + l15, lg * 16);
      bf16x8 kf1 = *(const bf16x8*)swz(&kbuf[cur][0][0], ni * 16 + l15, 64 + lg * 16);
      s[ni] = __builtin_amdgcn_mfma_f32_16x16x32_bf16(kf0, qf0, s[ni], 0, 0, 0);
      s[ni] = __builtin_amdgcn_mfma_f32_16x16x32_bf16(kf1, qf1, s[ni], 0, 0, 0);
    }
    __builtin_amdgcn_s_setprio(0);

    // online softmax in log2 domain, deferred-max (THR = 8)
    float tm = fmaxf(fmaxf(fmaxf(s[0][0], s[0][1]), fmaxf(s[0][2], s[0][3])),
                     fmaxf(fmaxf(s[1][0], s[1][1]), fmaxf(s[1][2], s[1][3])));
    tm = fmaxf(tm, fmaxf(fmaxf(fmaxf(s[2][0], s[2][1]), fmaxf(s[2][2], s[2][3])),
                         fmaxf(fmaxf(s[3][0], s[3][1]), fmaxf(s[3][2], s[3][3]))));
    tm = fmaxf(tm, __shfl_xor(tm, 16));
    tm = fmaxf(tm, __shfl_xor(tm, 32));
    if (__any(tm > mrun + 8.f)) {
      const float mnew = fmaxf(mrun, tm);
      const float al = fast_exp2(mrun - mnew);
      mrun = mnew;
      lrun *= al;
      for (int di = 0; di < 4; di++) oacc[di] *= al;
    }
    float rs = 0.f;
    for (int ni = 0; ni < 4; ni++) {
      bf16x4 pk;
      for (int r = 0; r < 4; r++) {
        const float p = fast_exp2(s[ni][r] - mrun);
        rs += p;
        pk[r] = (__bf16)p;
      }
      *(bf16x4*)swz(&p_lds[0][0], wv * 16 + l15, 32 * ni + 8 * lg) = pk;
    }
    rs += __shfl_xor(rs, 16);
    rs += __shfl_xor(rs, 32);
    lrun += rs;
    asm volatile("" ::: "memory");  // P writes (wave-private) before PV reads

    // O^T += V^T P
    __builtin_amdgcn_s_setprio(1);
    for (int kk = 0; kk < 2; kk++) {
      bf16x8 pf = *(const bf16x8*)swz(&p_lds[0][0], wv * 16 + l15, 64 * kk + 16 * lg);
      for (int di = 0; di < 4; di++) {
        bf16x8 vf = *(const bf16x8*)swz(&vtbuf[cur][0][0], di * 16 + l15, 64 * kk + 16 * lg);
        oacc[di] = __builtin_amdgcn_mfma_f32_16x16x32_bf16(vf, pf, oacc[di], 0, 0, 0);
      }
    }
    __builtin_amdgcn_s_setprio(0);

    if (have) {
      const int nxt = cur ^ 1;
      *(uint4*)swz(&kbuf[nxt][0][0], srow, sce * 2) = pka;
      *(uint4*)swz(&kbuf[nxt][0][0], srow, sce * 2 + 16) = pkc;
      *(uint4*)swz(&vtbuf[nxt][0][0], srow, sce * 2) = pva;
      *(uint4*)swz(&vtbuf[nxt][0][0], srow, sce * 2 + 16) = pvc;
      __syncthreads();
    }
    cur ^= 1;
  }

  // epilogue: normalize, per-wave transpose O^T -> O in p_lds, store coalesced
  const float inv = 1.f / lrun;
  for (int di = 0; di < 4; di++) {
    bf16x4 ov;
    for (int r = 0; r < 4; r++) ov[r] = (__bf16)(oacc[di][r] * inv);
    *(bf16x4*)swz(&p_lds[0][0], wv * 16 + l15, 32 * di + 8 * lg) = ov;
  }
  asm volatile("" ::: "memory");
  {
    const int orow = lane >> 2, oce = (lane & 3) * 16;
    uint4 o0 = *(uint4*)swz(&p_lds[0][0], wv * 16 + orow, oce * 2);
    uint4 o1 = *(uint4*)swz(&p_lds[0][0], wv * 16 + orow, oce * 2 + 16);
    const int b = bh >> 2, h = bh & 3;
    __bf16* dst = attout + ((size_t)b * N_ + qbase + wv * 16 + orow) * C_ + h * 64 + oce;
    *(uint4*)dst = o0;
    *(uint4*)(dst + 8) = o1;
  }
}

extern "C" void kernel_launch(void* const* d_in, const int* in_sizes, int n_in,
                              void* d_out, int out_size, void* d_ws,
                              size_t ws_size, hipStream_t stream) {
  const float* query = (const float*)d_in[0];
  const float* key_ = (const float*)d_in[1];
  const float* value = (const float*)d_in[2];
  const float* wq = (const float*)d_in[3];
  const float* bq = (const float*)d_in[4];
  const float* wk = (const float*)d_in[5];
  const float* bk = (const float*)d_in[6];
  const float* wv = (const float*)d_in[7];
  const float* bv = (const float*)d_in[8];
  const float* wm = (const float*)d_in[9];
  const float* bm = (const float*)d_in[10];

  const size_t per = (size_t)BH_ * N_ * D_;  // 4M elems = 8MB bf16
  __bf16* qb = (__bf16*)d_ws;
  __bf16* kb = qb + per;
  __bf16* vtb = kb + per;
  __bf16* attout = vtb + per;  // [B][N][256], k = h*64+d
  __bf16* wfq = attout + per;  // 64K elems each
  __bf16* wfk = wfq + 65536;
  __bf16* wfv = wfk + 65536;
  __bf16* wfm = wfv + 65536;

  dim3 blk(256);
  W4 wp{wq, wk, wv, wm, wfq, wfk, wfv, wfm};
  wcvt_kernel<<<dim3(32, 4), blk, 0, stream>>>(wp);

  qkv_proj_kernel<<<3072, blk, 0, stream>>>(query, key_, value, wfq, wfk, wfv,
                                            bq, bk, bv, qb, kb, vtb);
  attn_kernel<<<1024, blk, 0, stream>>>(qb, kb, vtb, attout);
  final_proj_kernel<<<1024, blk, 0, stream>>>(attout, wfm, bm, (float*)d_out);
}